// Round 7
// baseline (1205.214 us; speedup 1.0000x reference)
//
#include <hip/hip_runtime.h>

typedef unsigned short u16;
typedef unsigned int u32;
typedef __attribute__((ext_vector_type(8))) short short8;
typedef __attribute__((ext_vector_type(4))) u16 ushort4_t;
typedef __attribute__((ext_vector_type(4))) float fx4;

#define DIMK 2048
#define NBLK 2000

__device__ __forceinline__ u16 f2bf(float f) {
  u32 u = __float_as_uint(f);
  u32 r = (u + 0x7fffu + ((u >> 16) & 1u)) >> 16;
  return (u16)r;
}

__device__ __forceinline__ u32 fkey(float f) {
  u32 u = __float_as_uint(f);
  return (u & 0x80000000u) ? ~u : (u | 0x80000000u);
}
__device__ __forceinline__ float dekey(u32 k) {
  u32 u = (k & 0x80000000u) ? (k ^ 0x80000000u) : ~k;
  return __uint_as_float(u);
}

// one wave per row; block = 4 waves = 4 rows. No LDS, no __syncthreads.
__global__ __launch_bounds__(256) void norm_rows_x(const float* __restrict__ x,
                                                   u16* __restrict__ Xn)
{
  const int wv = threadIdx.x >> 6, lane = threadIdx.x & 63;
  const int row = blockIdx.x * 4 + wv;
  const float4* xr = (const float4*)(x + (size_t)row * DIMK);
  float4 v[8];
  float ss = 0.f;
#pragma unroll
  for (int j = 0; j < 8; j++) {
    v[j] = xr[j * 64 + lane];
    ss += v[j].x*v[j].x + v[j].y*v[j].y + v[j].z*v[j].z + v[j].w*v[j].w;
  }
#pragma unroll
  for (int off = 1; off < 64; off <<= 1) ss += __shfl_xor(ss, off);
  float inv = 1.0f / fmaxf(sqrtf(ss), 1e-12f);
  ushort4_t* o = (ushort4_t*)(Xn + (size_t)row * DIMK);
#pragma unroll
  for (int j = 0; j < 8; j++) {
    ushort4_t t;
    t[0] = f2bf(v[j].x * inv); t[1] = f2bf(v[j].y * inv);
    t[2] = f2bf(v[j].z * inv); t[3] = f2bf(v[j].w * inv);
    o[j * 64 + lane] = t;
  }
}

__global__ __launch_bounds__(256) void norm_rows_w(const float* __restrict__ w,
                                                   u16* __restrict__ Wn,
                                                   u16* __restrict__ Wb)
{
  const int wv = threadIdx.x >> 6, lane = threadIdx.x & 63;
  const int row = blockIdx.x * 4 + wv;
  ushort4_t* on_ = (ushort4_t*)(Wn + (size_t)row * DIMK);
  ushort4_t* ob_ = (ushort4_t*)(Wb + (size_t)row * DIMK);
  if (row < NBLK) {
    const float4* wr_ = (const float4*)(w + (size_t)row * DIMK);
    float4 v[8];
    float ss = 0.f;
#pragma unroll
    for (int j = 0; j < 8; j++) {
      v[j] = wr_[j * 64 + lane];
      ss += v[j].x*v[j].x + v[j].y*v[j].y + v[j].z*v[j].z + v[j].w*v[j].w;
    }
#pragma unroll
    for (int off = 1; off < 64; off <<= 1) ss += __shfl_xor(ss, off);
    float inv = 1.0f / fmaxf(sqrtf(ss), 1e-12f);
#pragma unroll
    for (int j = 0; j < 8; j++) {
      ushort4_t tn, tb;
      tn[0] = f2bf(v[j].x * inv); tn[1] = f2bf(v[j].y * inv);
      tn[2] = f2bf(v[j].z * inv); tn[3] = f2bf(v[j].w * inv);
      tb[0] = f2bf(v[j].x); tb[1] = f2bf(v[j].y);
      tb[2] = f2bf(v[j].z); tb[3] = f2bf(v[j].w);
      on_[j * 64 + lane] = tn;
      ob_[j * 64 + lane] = tb;
    }
  } else {
    ushort4_t z = ushort4_t{0, 0, 0, 0};
#pragma unroll
    for (int j = 0; j < 8; j++) { on_[j * 64 + lane] = z; ob_[j * 64 + lane] = z; }
  }
}

// ---------------------------------------------------------------------------
// gram r7: no-LDS direct-fragment GEMM. 128x128 tile, 4 waves (2x2, 64x64
// per wave). Fragment layout = what the verified LDS path delivered:
// lane(quad,lc) holds [row=base+lc][k = k0 + quad*8 .. +8] (16B short8).
// W (8 MB bf16) is L2/L3-resident; wr/wc duplicate reads are same-CU L1 hits.
// No barriers -> free-running waves, latency hidden by TLP. Symmetric: only
// by <= bx tiles, off-diagonal doubled.
// ---------------------------------------------------------------------------
__global__ __launch_bounds__(256) void gram_kernel(const u16* __restrict__ Wb,
                                                   float* __restrict__ divsum)
{
  const int bx = blockIdx.x, by = blockIdx.y;
  if (by > bx) return;
  const int tid = threadIdx.x, wv = tid >> 6, lane = tid & 63;
  const int wr = wv & 1, wc = wv >> 1, quad = lane >> 4, lc = lane & 15;
  const int i0 = by * 128, j0 = bx * 128;

  const u16* Abase = Wb + (size_t)(i0 + wr * 64 + lc) * DIMK + quad * 8;
  const u16* Bbase = Wb + (size_t)(j0 + wc * 64 + lc) * DIMK + quad * 8;

  fx4 acc[4][4];
#pragma unroll
  for (int mi = 0; mi < 4; mi++)
#pragma unroll
    for (int ni = 0; ni < 4; ni++)
      acc[mi][ni] = fx4{0.f, 0.f, 0.f, 0.f};

#pragma unroll 1
  for (int t = 0; t < DIMK / 32; ++t) {
    const int k0 = t * 32;
    short8 af[4], bfr[4];
#pragma unroll
    for (int mi = 0; mi < 4; mi++)
      af[mi] = *(const short8*)(Abase + (size_t)mi * 16 * DIMK + k0);
#pragma unroll
    for (int ni = 0; ni < 4; ni++)
      bfr[ni] = *(const short8*)(Bbase + (size_t)ni * 16 * DIMK + k0);
#pragma unroll
    for (int mi = 0; mi < 4; mi++)
#pragma unroll
      for (int ni = 0; ni < 4; ni++)
        acc[mi][ni] = __builtin_amdgcn_mfma_f32_16x16x32_bf16(af[mi], bfr[ni], acc[mi][ni], 0, 0, 0);
  }

  const float mult = (bx == by) ? 1.0f : 2.0f;
  float local = 0.f;
#pragma unroll
  for (int mi = 0; mi < 4; mi++) {
#pragma unroll
    for (int ni = 0; ni < 4; ni++) {
#pragma unroll
      for (int r = 0; r < 4; r++) {
        int i = i0 + wr * 64 + mi * 16 + quad * 4 + r;
        int j = j0 + wc * 64 + ni * 16 + lc;
        float g = acc[mi][ni][r];
        float d = (i == j && i < NBLK) ? 1.0f : 0.0f;
        float e = g - d;
        local += e * e;
      }
    }
  }
  local *= mult;
#pragma unroll
  for (int off = 1; off < 64; off <<= 1) local += __shfl_xor(local, off);
  if (lane == 0) atomicAdd(divsum, local);
}

// ---------------------------------------------------------------------------
// att r7: NO-LDS direct-fragment GEMM. 128x256 tile, 4 waves (2Mx2N, each
// 64x128, acc[4][8]=128 regs). Rationale (r6 post-mortem): MfmaUtil pinned
// at ~41% across 1-phase/2-phase/1-block/2-block LDS variants — the barrier-
// lockstep serial chain (LDS 1152 + MFMA 1242 cyc/pair-step) is the binding
// constraint while NO pipe exceeds 41%. Working set is L2-resident under the
// XCD chunking (4 A-panels 2MB + B-tile 1MB <= 4MB/XCD), so LDS staging is
// pure overhead (m169). Direct per-lane fragment loads reproduce the exact
// layout the verified LDS path delivered: af[mi] lane(quad,lc) =
// Xn[row0+wr*64+mi*16+lc][k0+quad*8..+8]; bfr[ni] likewise from Wn.
// No barriers: waves free-run and self-skew -> cross-wave MFMA||VMEM||VALU
// co-issue (m114). Regs ~195 -> 2 waves/SIMD via (256,2), no spill (r4).
// Grid 2048 = 256 row-panels x 8 col-tiles; per-XCD 4-panel x 8-col subgroup
// order keeps the working set L2-hot.
// ---------------------------------------------------------------------------
__global__ __launch_bounds__(256, 2) void att_kernel(const u16* __restrict__ Xn,
                                                     const u16* __restrict__ Wn,
                                                     const int* __restrict__ mask,
                                                     u32* __restrict__ top1k,
                                                     float* __restrict__ s)
{
  const int orig  = blockIdx.x;
  const int xcd   = orig & 7;
  const int local = orig >> 3;                  // 0..255
  const int yb    = xcd * 32 + ((local >> 5) << 2) + (local & 3);  // row panel
  const int xb    = (local >> 2) & 7;                              // col tile
  const int row0 = yb << 7, col0 = xb << 8;

  const int tid = threadIdx.x, wv = tid >> 6, lane = tid & 63;
  const int wr = wv >> 1, wc = wv & 1, quad = lane >> 4, lc = lane & 15;

  const u16* Abase = Xn + (size_t)(row0 + wr * 64 + lc) * DIMK + quad * 8;
  const u16* Bbase = Wn + (size_t)(col0 + wc * 128 + lc) * DIMK + quad * 8;

  fx4 acc[4][8];
#pragma unroll
  for (int mi = 0; mi < 4; mi++)
#pragma unroll
    for (int ni = 0; ni < 8; ni++)
      acc[mi][ni] = fx4{0.f, 0.f, 0.f, 0.f};

#pragma unroll 1
  for (int t = 0; t < DIMK / 32; ++t) {
    const int k0 = t * 32;
    short8 af[4], bfr[8];
#pragma unroll
    for (int mi = 0; mi < 4; mi++)
      af[mi] = *(const short8*)(Abase + (size_t)mi * 16 * DIMK + k0);
#pragma unroll
    for (int ni = 0; ni < 8; ni++)
      bfr[ni] = *(const short8*)(Bbase + (size_t)ni * 16 * DIMK + k0);
#pragma unroll
    for (int mi = 0; mi < 4; mi++)
#pragma unroll
      for (int ni = 0; ni < 8; ni++)
        acc[mi][ni] = __builtin_amdgcn_mfma_f32_16x16x32_bf16(af[mi], bfr[ni], acc[mi][ni], 0, 0, 0);
  }

  // ---- per-row max over this tile's 256 cols ----
#pragma unroll
  for (int mi = 0; mi < 4; mi++) {
#pragma unroll
    for (int r = 0; r < 4; r++) {
      float v = -3.0e38f;
#pragma unroll
      for (int ni = 0; ni < 8; ni++) {
        int col = col0 + wc * 128 + ni * 16 + lc;
        float av = acc[mi][ni][r];
        v = (col < NBLK && av > v) ? av : v;
      }
      v = fmaxf(v, __shfl_xor(v, 1));
      v = fmaxf(v, __shfl_xor(v, 2));
      v = fmaxf(v, __shfl_xor(v, 4));
      v = fmaxf(v, __shfl_xor(v, 8));
      if (lc == 0) {
        int row = row0 + wr * 64 + mi * 16 + quad * 4 + r;
        atomicMax(&top1k[row], fkey(v));
      }
    }
  }

  // ---- masked column sums for first half-batch -> s[b][col] ----
  if (yb < 128) {
    const int b = yb >> 3;
    float sv[8] = {0.f, 0.f, 0.f, 0.f, 0.f, 0.f, 0.f, 0.f};
#pragma unroll
    for (int mi = 0; mi < 4; mi++) {
#pragma unroll
      for (int r = 0; r < 4; r++) {
        float mval = (float)mask[row0 + wr * 64 + mi * 16 + quad * 4 + r];
#pragma unroll
        for (int ni = 0; ni < 8; ni++)
          sv[ni] += mval * acc[mi][ni][r];
      }
    }
#pragma unroll
    for (int ni = 0; ni < 8; ni++) {
      float v = sv[ni];
      v += __shfl_xor(v, 16);
      v += __shfl_xor(v, 32);
      int col = col0 + wc * 128 + ni * 16 + lc;
      if (quad == 0 && col < NBLK)
        atomicAdd(&s[b * 2048 + col], v);
    }
  }
}

// softmax + finalize merged: one block, 16 waves.
__global__ __launch_bounds__(1024) void tail_kernel(const float* __restrict__ s,
                                                    const u32* __restrict__ top1k,
                                                    const int* __restrict__ mask,
                                                    const float* __restrict__ divsum,
                                                    float* __restrict__ out)
{
  const int tid = threadIdx.x;
  const int w = tid >> 6, lane = tid & 63;     // 16 waves, wave w -> softmax row w
  __shared__ float mx_s[16], ise_s[16];
  __shared__ float red[16];
  __shared__ float sMin[32];

  const float* sb = s + w * 2048;
  float mx = -3.0e38f;
  for (int n = lane; n < NBLK; n += 64) mx = fmaxf(mx, sb[n]);
#pragma unroll
  for (int off = 1; off < 64; off <<= 1) mx = fmaxf(mx, __shfl_xor(mx, off));
  float se = 0.f;
  for (int n = lane; n < NBLK; n += 64) se += expf(sb[n] - mx);
#pragma unroll
  for (int off = 1; off < 64; off <<= 1) se += __shfl_xor(se, off);
  if (lane == 0) { mx_s[w] = mx; ise_s[w] = 1.0f / (se * 16.0f); }
  __syncthreads();

  float ssq = 0.f;
  for (int n = tid; n < NBLK; n += 1024) {
    float v = 0.f;
#pragma unroll
    for (int b = 0; b < 16; b++)
      v += expf(s[b * 2048 + n] - mx_s[b]) * ise_s[b];
    ssq += v * v;
  }
#pragma unroll
  for (int off = 1; off < 64; off <<= 1) ssq += __shfl_xor(ssq, off);
  if (lane == 0) red[w] = ssq;

  const int b = tid >> 5, li = tid & 31;
  float mn = 3.0e38f;
  for (int t = li; t < 1024; t += 32) {
    int idx = b * 1024 + t;
    if (mask[idx] > 0) mn = fminf(mn, dekey(top1k[idx]));
  }
#pragma unroll
  for (int off = 1; off < 32; off <<= 1) mn = fminf(mn, __shfl_xor(mn, off));
  if (li == 0) sMin[b] = mn;
  __syncthreads();

  if (tid == 0) {
    float m0 = 0.f, m1 = 0.f;
    for (int i = 0; i < 16; i++) { m0 += sMin[i]; m1 += sMin[16 + i]; }
    m0 *= (1.0f / 16.0f); m1 *= (1.0f / 16.0f);
    float sq = 0.f;
    for (int i = 0; i < 16; i++) sq += red[i];
    out[0] = 0.2f * sqrtf(divsum[0]);
    out[1] = 2.0f - m0 + m1;
    out[2] = 0.5f * sqrtf(sq);
  }
}

extern "C" void kernel_launch(void* const* d_in, const int* in_sizes, int n_in,
                              void* d_out, int out_size, void* d_ws, size_t ws_size,
                              hipStream_t stream) {
  const float* x    = (const float*)d_in[0];   // [32,1024,2048] f32
  const int*   mask = (const int*)d_in[1];     // [32,1024] i32
  const float* w    = (const float*)d_in[2];   // [2000,2048] f32
  float* out = (float*)d_out;

  char* ws = (char*)d_ws;
  // layout: [top1k 128KB][s 128KB][tmp 8KB unused][divsum 256B][Xn 128MB][Wn 8MB][Wb 8MB]
  u32*   top1k  = (u32*)(ws);
  float* s      = (float*)(ws + 131072);
  float* divsum = (float*)(ws + 270336);
  u16*   Xn     = (u16*)(ws + 270592);
  u16*   Wn     = (u16*)(ws + 270592 + 134217728ull);
  u16*   Wb     = (u16*)(ws + 270592 + 134217728ull + 8388608ull);

  hipMemsetAsync(ws, 0, 270592, stream);  // zero accumulators + top1 keys

  norm_rows_w<<<dim3(512), dim3(256), 0, stream>>>(w, Wn, Wb);
  norm_rows_x<<<dim3(8192), dim3(256), 0, stream>>>(x, Xn);
  gram_kernel<<<dim3(16, 16), dim3(256), 0, stream>>>(Wb, divsum);
  att_kernel<<<dim3(2048), dim3(256), 0, stream>>>(Xn, Wn, mask, top1k, s);
  tail_kernel<<<dim3(1), dim3(1024), 0, stream>>>(s, top1k, mask, divsum, out);
}